// Round 1
// baseline (1100.814 us; speedup 1.0000x reference)
//
#include <hip/hip_runtime.h>

#define NEG 0.2f

// ---------- order-preserving float<->uint key for atomicMax on floats ----------
__device__ __forceinline__ unsigned fkey(float f) {
  unsigned u = __float_as_uint(f);
  return (u & 0x80000000u) ? ~u : (u | 0x80000000u);
}
__device__ __forceinline__ float fdec(unsigned k) {
  return (k & 0x80000000u) ? __uint_as_float(k ^ 0x80000000u) : __uint_as_float(~k);
}

// ---------- detect whether edge_index arrived as int64 or int32 ----------
// If data is int64 with values in [0,N), the int64 view of the first 64 entries
// is all-valid. If data is int32, the int64 view combines pairs -> huge values
// almost surely. P(false positive) = (1/N)^64 ~ 0.
__global__ void detect_idx64(const void* __restrict__ ei, int n_nodes, int* __restrict__ flag) {
  const long long* e64 = (const long long*)ei;
  long long v = e64[threadIdx.x];
  bool ok = (v >= 0 && v < (long long)n_nodes);
  unsigned long long b = __ballot(ok);
  if (threadIdx.x == 0) *flag = (b == ~0ull) ? 1 : 0;
}

__device__ __forceinline__ void get_edge(const void* __restrict__ ei, int is64, int e, int E,
                                         int& src, int& dst) {
  if (e >= E) { src = e - E; dst = e - E; return; }  // self-loops appended
  if (is64) {
    const long long* p = (const long long*)ei;
    src = (int)p[e];
    dst = (int)p[(size_t)E + e];
  } else {
    const int* p = (const int*)ei;
    src = p[e];
    dst = p[E + e];
  }
}

// ---------- fused dual GEMM: xl = X@Wl, xr = X@Wr  (X read once) ----------
// block = 256 threads, each block computes ROWS=256/C rows x C cols of both outputs.
template <int K, int C>
__global__ void dual_gemm(const float* __restrict__ X,
                          const float* __restrict__ Wl,
                          const float* __restrict__ Wr,
                          float* __restrict__ xl, float* __restrict__ xr, int nrows) {
  constexpr int ROWS = 256 / C;
  __shared__ float xs[ROWS * K];
  int r = threadIdx.x / C;
  int c = threadIdx.x % C;
  int row0 = blockIdx.x * ROWS;
  for (int idx = threadIdx.x; idx < ROWS * K; idx += 256) {
    int rr = idx / K, kk = idx - rr * K;
    int g = row0 + rr;
    xs[idx] = (g < nrows) ? X[(size_t)g * K + kk] : 0.f;
  }
  __syncthreads();
  int row = row0 + r;
  if (row >= nrows) return;
  float al = 0.f, ar = 0.f;
#pragma unroll 8
  for (int k = 0; k < K; ++k) {
    float xv = xs[r * K + k];
    al = fmaf(xv, Wl[k * C + c], al);
    ar = fmaf(xv, Wr[k * C + c], ar);
  }
  xl[(size_t)row * C + c] = al;
  xr[(size_t)row * C + c] = ar;
}

// ---------- layer 1 (H=2, C=64): one wave per edge ----------
__global__ void edge_logits1_k(const float* __restrict__ xl, const float* __restrict__ xr,
                               const void* __restrict__ ei, const int* __restrict__ flag,
                               const float* __restrict__ att,
                               float* __restrict__ logits, unsigned* __restrict__ mkey,
                               int E, int Etot) {
  int wv = blockIdx.x * 4 + (threadIdx.x >> 6);
  int lane = threadIdx.x & 63;
  if (wv >= Etot) return;
  int src, dst;
  get_edge(ei, *flag, wv, E, src, dst);
  const float* pl = xl + (size_t)src * 128;
  const float* pr = xr + (size_t)dst * 128;
  float v0 = pl[lane] + pr[lane];
  float v1 = pl[64 + lane] + pr[64 + lane];
  v0 = v0 > 0.f ? v0 : NEG * v0;
  v1 = v1 > 0.f ? v1 : NEG * v1;
  float t0 = v0 * att[lane];
  float t1 = v1 * att[64 + lane];
#pragma unroll
  for (int o = 32; o; o >>= 1) {
    t0 += __shfl_xor(t0, o);
    t1 += __shfl_xor(t1, o);
  }
  if (lane == 0) {
    logits[(size_t)wv * 2 + 0] = t0;
    logits[(size_t)wv * 2 + 1] = t1;
    atomicMax(&mkey[dst * 2 + 0], fkey(t0));
  }
  if (lane == 1) {
    atomicMax(&mkey[dst * 2 + 1], fkey(t1));
  }
}

__global__ void edge_accum1_k(const float* __restrict__ xl,
                              const void* __restrict__ ei, const int* __restrict__ flag,
                              const float* __restrict__ logits, const unsigned* __restrict__ mkey,
                              float* __restrict__ s, float* __restrict__ accum,
                              int E, int Etot) {
  int wv = blockIdx.x * 4 + (threadIdx.x >> 6);
  int lane = threadIdx.x & 63;
  if (wv >= Etot) return;
  int src, dst;
  get_edge(ei, *flag, wv, E, src, dst);
  float l0 = logits[(size_t)wv * 2 + 0];
  float l1 = logits[(size_t)wv * 2 + 1];
  float p0 = __expf(l0 - fdec(mkey[dst * 2 + 0]));
  float p1 = __expf(l1 - fdec(mkey[dst * 2 + 1]));
  if (lane == 0) atomicAdd(&s[dst * 2 + 0], p0);
  if (lane == 1) atomicAdd(&s[dst * 2 + 1], p1);
  const float* pl = xl + (size_t)src * 128;
  float* pa = accum + (size_t)dst * 128;
  atomicAdd(&pa[lane], p0 * pl[lane]);
  atomicAdd(&pa[64 + lane], p1 * pl[64 + lane]);
}

__global__ void finalize1_k(const float* __restrict__ accum, const float* __restrict__ s,
                            const float* __restrict__ b, float* __restrict__ h1, int total) {
  int i = blockIdx.x * 256 + threadIdx.x;
  if (i >= total) return;
  int node = i >> 7, ch = i & 127, h = ch >> 6;
  float v = accum[i] / s[node * 2 + h] + b[ch];
  h1[i] = v > 0.f ? v : __expf(v) - 1.f;  // ELU
}

// ---------- layer 2 (H=1, C=32): half-wave (32 lanes) per edge ----------
__global__ void edge_logits2_k(const float* __restrict__ xl, const float* __restrict__ xr,
                               const void* __restrict__ ei, const int* __restrict__ flag,
                               const float* __restrict__ att,
                               float* __restrict__ logits, unsigned* __restrict__ mkey,
                               int E, int Etot) {
  int e = blockIdx.x * 8 + (threadIdx.x >> 5);
  int lane = threadIdx.x & 31;
  if (e >= Etot) return;
  int src, dst;
  get_edge(ei, *flag, e, E, src, dst);
  float v = xl[(size_t)src * 32 + lane] + xr[(size_t)dst * 32 + lane];
  v = v > 0.f ? v : NEG * v;
  float t = v * att[lane];
#pragma unroll
  for (int o = 16; o; o >>= 1) t += __shfl_xor(t, o);  // stays within 32-lane half
  if (lane == 0) {
    logits[e] = t;
    atomicMax(&mkey[dst], fkey(t));
  }
}

__global__ void edge_accum2_k(const float* __restrict__ xl,
                              const void* __restrict__ ei, const int* __restrict__ flag,
                              const float* __restrict__ logits, const unsigned* __restrict__ mkey,
                              float* __restrict__ s, float* __restrict__ accum,
                              int E, int Etot) {
  int e = blockIdx.x * 8 + (threadIdx.x >> 5);
  int lane = threadIdx.x & 31;
  if (e >= Etot) return;
  int src, dst;
  get_edge(ei, *flag, e, E, src, dst);
  float p = __expf(logits[e] - fdec(mkey[dst]));
  if (lane == 0) atomicAdd(&s[dst], p);
  atomicAdd(&accum[(size_t)dst * 32 + lane], p * xl[(size_t)src * 32 + lane]);
}

__global__ void finalize2_k(const float* __restrict__ accum, const float* __restrict__ s,
                            const float* __restrict__ b, float* __restrict__ out, int total) {
  int i = blockIdx.x * 256 + threadIdx.x;
  if (i >= total) return;
  int node = i >> 5, c = i & 31;
  out[i] = accum[i] / s[node] + b[c];
}

extern "C" void kernel_launch(void* const* d_in, const int* in_sizes, int n_in,
                              void* d_out, int out_size, void* d_ws, size_t ws_size,
                              hipStream_t stream) {
  const float* x    = (const float*)d_in[0];
  const void*  ei   = d_in[1];
  const float* Wl1  = (const float*)d_in[2];
  const float* Wr1  = (const float*)d_in[3];
  const float* att1 = (const float*)d_in[4];
  const float* b1   = (const float*)d_in[5];
  const float* Wl2  = (const float*)d_in[6];
  const float* Wr2  = (const float*)d_in[7];
  const float* att2 = (const float*)d_in[8];
  const float* b2   = (const float*)d_in[9];

  const int N = in_sizes[0] / 128;
  const int E = in_sizes[1] / 2;
  const int Etot = E + N;
  float* out = (float*)d_out;

  // ---------------- workspace layout (with layer-2 overlay onto xl1/xr1) ----
  char* ws = (char*)d_ws;
  size_t off = 0;
  auto alloc = [&](size_t bytes) {
    void* p = ws + off;
    off += (bytes + 255) & ~(size_t)255;
    return p;
  };
  float*    xl1    = (float*)alloc((size_t)N * 128 * 4);  // region1 start
  float*    xr1    = (float*)alloc((size_t)N * 128 * 4);
  size_t region1_end = off;
  float*    logits1 = (float*)alloc((size_t)Etot * 2 * 4);
  unsigned* mkey1   = (unsigned*)alloc((size_t)N * 2 * 4);
  float*    s1      = (float*)alloc((size_t)N * 2 * 4);
  float*    accum1  = (float*)alloc((size_t)N * 128 * 4);
  float*    h1      = (float*)alloc((size_t)N * 128 * 4);
  int*      flag    = (int*)alloc(256);
  (void)ws_size; (void)region1_end; (void)out_size; (void)n_in;

  // layer-2 buffers overlay region1 (xl1/xr1 dead after edge_accum1_k)
  size_t o2 = 0;
  auto alloc2 = [&](size_t bytes) {
    void* p = ws + o2;
    o2 += (bytes + 255) & ~(size_t)255;
    return p;
  };
  float*    xl2     = (float*)alloc2((size_t)N * 32 * 4);
  float*    xr2     = (float*)alloc2((size_t)N * 32 * 4);
  float*    logits2 = (float*)alloc2((size_t)Etot * 4);
  unsigned* mkey2   = (unsigned*)alloc2((size_t)N * 4);
  float*    s2      = (float*)alloc2((size_t)N * 4);
  float*    accum2  = (float*)alloc2((size_t)N * 32 * 4);

  // ---------------- layer 1 ----------------
  hipLaunchKernelGGL(detect_idx64, dim3(1), dim3(64), 0, stream, ei, N, flag);
  hipMemsetAsync(mkey1, 0, (size_t)N * 2 * 4, stream);
  hipMemsetAsync(s1, 0, (size_t)N * 2 * 4, stream);
  hipMemsetAsync(accum1, 0, (size_t)N * 128 * 4, stream);

  hipLaunchKernelGGL((dual_gemm<128, 128>), dim3((N + 1) / 2), dim3(256), 0, stream,
                     x, Wl1, Wr1, xl1, xr1, N);
  hipLaunchKernelGGL(edge_logits1_k, dim3((Etot + 3) / 4), dim3(256), 0, stream,
                     xl1, xr1, ei, flag, att1, logits1, mkey1, E, Etot);
  hipLaunchKernelGGL(edge_accum1_k, dim3((Etot + 3) / 4), dim3(256), 0, stream,
                     xl1, ei, flag, logits1, mkey1, s1, accum1, E, Etot);
  hipLaunchKernelGGL(finalize1_k, dim3((N * 128 + 255) / 256), dim3(256), 0, stream,
                     accum1, s1, b1, h1, N * 128);

  // ---------------- layer 2 ----------------
  hipMemsetAsync(mkey2, 0, (size_t)N * 4, stream);
  hipMemsetAsync(s2, 0, (size_t)N * 4, stream);
  hipMemsetAsync(accum2, 0, (size_t)N * 32 * 4, stream);

  hipLaunchKernelGGL((dual_gemm<128, 32>), dim3((N + 7) / 8), dim3(256), 0, stream,
                     h1, Wl2, Wr2, xl2, xr2, N);
  hipLaunchKernelGGL(edge_logits2_k, dim3((Etot + 7) / 8), dim3(256), 0, stream,
                     xl2, xr2, ei, flag, att2, logits2, mkey2, E, Etot);
  hipLaunchKernelGGL(edge_accum2_k, dim3((Etot + 7) / 8), dim3(256), 0, stream,
                     xl2, ei, flag, logits2, mkey2, s2, accum2, E, Etot);
  hipLaunchKernelGGL(finalize2_k, dim3((N * 32 + 255) / 256), dim3(256), 0, stream,
                     accum2, s2, b2, out, N * 32);
}

// Round 2
// 490.332 us; speedup vs baseline: 2.2450x; 2.2450x over previous
//
#include <hip/hip_runtime.h>

#define NEG 0.2f

// ---------- detect whether edge_index arrived as int64 or int32 ----------
__global__ void detect_idx64(const void* __restrict__ ei, int n_nodes, int* __restrict__ flag) {
  const long long* e64 = (const long long*)ei;
  long long v = e64[threadIdx.x];
  bool ok = (v >= 0 && v < (long long)n_nodes);
  unsigned long long b = __ballot(ok);
  if (threadIdx.x == 0) *flag = (b == ~0ull) ? 1 : 0;
}

__device__ __forceinline__ void get_edge(const void* __restrict__ ei, int is64, int e, int E,
                                         int& src, int& dst) {
  if (e >= E) { src = e - E; dst = e - E; return; }  // self-loops appended
  if (is64) {
    const long long* p = (const long long*)ei;
    src = (int)p[e];
    dst = (int)p[(size_t)E + e];
  } else {
    const int* p = (const int*)ei;
    src = p[e];
    dst = p[E + e];
  }
}

// ---------- CSR build: histogram -> scan -> scatter ----------
__global__ void hist_k(const void* __restrict__ ei, const int* __restrict__ flag,
                       int* __restrict__ count, int E, int Etot) {
  int e = blockIdx.x * 256 + threadIdx.x;
  if (e >= Etot) return;
  int src, dst;
  get_edge(ei, *flag, e, E, src, dst);
  (void)src;
  atomicAdd(&count[dst], 1);
}

__global__ void scan1_k(const int* __restrict__ count, int* __restrict__ bsum, int n) {
  __shared__ int sd[256];
  int i = blockIdx.x * 256 + threadIdx.x;
  sd[threadIdx.x] = (i < n) ? count[i] : 0;
  __syncthreads();
  for (int o = 128; o; o >>= 1) {
    if (threadIdx.x < o) sd[threadIdx.x] += sd[threadIdx.x + o];
    __syncthreads();
  }
  if (threadIdx.x == 0) bsum[blockIdx.x] = sd[0];
}

__global__ void scan2_k(int* __restrict__ bsum, int nb) {  // exclusive scan, 1 block, nb<=256
  __shared__ int sd[256];
  int v = (threadIdx.x < nb) ? bsum[threadIdx.x] : 0;
  sd[threadIdx.x] = v;
  __syncthreads();
  for (int o = 1; o < 256; o <<= 1) {
    int t = (threadIdx.x >= o) ? sd[threadIdx.x - o] : 0;
    __syncthreads();
    sd[threadIdx.x] += t;
    __syncthreads();
  }
  if (threadIdx.x < nb) bsum[threadIdx.x] = sd[threadIdx.x] - v;
}

__global__ void scan3_k(const int* __restrict__ count, const int* __restrict__ bsum,
                        int* __restrict__ off, int* __restrict__ cursor, int n, int etot) {
  __shared__ int sd[256];
  int i = blockIdx.x * 256 + threadIdx.x;
  int v = (i < n) ? count[i] : 0;
  sd[threadIdx.x] = v;
  __syncthreads();
  for (int o = 1; o < 256; o <<= 1) {
    int t = (threadIdx.x >= o) ? sd[threadIdx.x - o] : 0;
    __syncthreads();
    sd[threadIdx.x] += t;
    __syncthreads();
  }
  if (i < n) {
    int ex = bsum[blockIdx.x] + sd[threadIdx.x] - v;
    off[i] = ex;
    cursor[i] = ex;
  }
  if (i == 0) off[n] = etot;
}

__global__ void scatter_k(const void* __restrict__ ei, const int* __restrict__ flag,
                          int* __restrict__ cursor, int* __restrict__ bucket, int E, int Etot) {
  int e = blockIdx.x * 256 + threadIdx.x;
  if (e >= Etot) return;
  int src, dst;
  get_edge(ei, *flag, e, E, src, dst);
  int pos = atomicAdd(&cursor[dst], 1);
  bucket[pos] = src;
}

// ---------- fused dual GEMM: xl = X@Wl, xr = X@Wr  (X read once) ----------
template <int K, int C>
__global__ void dual_gemm(const float* __restrict__ X,
                          const float* __restrict__ Wl,
                          const float* __restrict__ Wr,
                          float* __restrict__ xl, float* __restrict__ xr, int nrows) {
  constexpr int ROWS = 256 / C;
  __shared__ float xs[ROWS * K];
  int r = threadIdx.x / C;
  int c = threadIdx.x % C;
  int row0 = blockIdx.x * ROWS;
  for (int idx = threadIdx.x; idx < ROWS * K; idx += 256) {
    int rr = idx / K, kk = idx - rr * K;
    int g = row0 + rr;
    xs[idx] = (g < nrows) ? X[(size_t)g * K + kk] : 0.f;
  }
  __syncthreads();
  int row = row0 + r;
  if (row >= nrows) return;
  float al = 0.f, ar = 0.f;
#pragma unroll 8
  for (int k = 0; k < K; ++k) {
    float xv = xs[r * K + k];
    al = fmaf(xv, Wl[k * C + c], al);
    ar = fmaf(xv, Wr[k * C + c], ar);
  }
  xl[(size_t)row * C + c] = al;
  xr[(size_t)row * C + c] = ar;
}

// ---------- layer 1 fused: one wave per node, online softmax ----------
__global__ void fused_layer1_k(const float* __restrict__ xl, const float* __restrict__ xr,
                               const int* __restrict__ off, const int* __restrict__ bucket,
                               const float* __restrict__ att, const float* __restrict__ b,
                               float* __restrict__ h1, int N) {
  int node = blockIdx.x * 4 + (threadIdx.x >> 6);
  int lane = threadIdx.x & 63;
  if (node >= N) return;
  float xr0 = xr[(size_t)node * 128 + lane];
  float xr1 = xr[(size_t)node * 128 + 64 + lane];
  float a0 = att[lane], a1 = att[64 + lane];
  float m0 = -INFINITY, m1 = -INFINITY, s0 = 0.f, s1 = 0.f, o0 = 0.f, o1 = 0.f;
  int jend = off[node + 1];
  int j = off[node];

  auto update = [&](float v0, float v1) {
    float e0 = v0 + xr0; e0 = e0 > 0.f ? e0 : NEG * e0;
    float e1 = v1 + xr1; e1 = e1 > 0.f ? e1 : NEG * e1;
    float t0 = e0 * a0, t1 = e1 * a1;
#pragma unroll
    for (int o = 32; o; o >>= 1) {
      t0 += __shfl_xor(t0, o);
      t1 += __shfl_xor(t1, o);
    }
    float nm0 = fmaxf(m0, t0), nm1 = fmaxf(m1, t1);
    float c0 = __expf(m0 - nm0), c1 = __expf(m1 - nm1);
    float p0 = __expf(t0 - nm0), p1 = __expf(t1 - nm1);
    s0 = s0 * c0 + p0;
    s1 = s1 * c1 + p1;
    o0 = o0 * c0 + p0 * v0;
    o1 = o1 * c1 + p1 * v1;
    m0 = nm0;
    m1 = nm1;
  };

  for (; j + 1 < jend; j += 2) {
    int sa = bucket[j], sb = bucket[j + 1];
    const float* pa = xl + (size_t)sa * 128;
    const float* pb = xl + (size_t)sb * 128;
    float va0 = pa[lane], va1 = pa[64 + lane];
    float vb0 = pb[lane], vb1 = pb[64 + lane];
    update(va0, va1);
    update(vb0, vb1);
  }
  if (j < jend) {
    const float* pa = xl + (size_t)bucket[j] * 128;
    update(pa[lane], pa[64 + lane]);
  }
  float v0 = o0 / s0 + b[lane];
  float v1 = o1 / s1 + b[64 + lane];
  h1[(size_t)node * 128 + lane]      = v0 > 0.f ? v0 : __expf(v0) - 1.f;  // ELU
  h1[(size_t)node * 128 + 64 + lane] = v1 > 0.f ? v1 : __expf(v1) - 1.f;
}

// ---------- layer 2 fused: half-wave per node ----------
__global__ void fused_layer2_k(const float* __restrict__ xl, const float* __restrict__ xr,
                               const int* __restrict__ off, const int* __restrict__ bucket,
                               const float* __restrict__ att, const float* __restrict__ b,
                               float* __restrict__ out, int N) {
  int node = blockIdx.x * 8 + (threadIdx.x >> 5);
  int lane = threadIdx.x & 31;
  if (node >= N) return;
  float xr0 = xr[(size_t)node * 32 + lane];
  float a0 = att[lane];
  float m = -INFINITY, s = 0.f, o = 0.f;
  int jend = off[node + 1];
  int j = off[node];

  auto update = [&](float v) {
    float e = v + xr0; e = e > 0.f ? e : NEG * e;
    float t = e * a0;
#pragma unroll
    for (int ofs = 16; ofs; ofs >>= 1) t += __shfl_xor(t, ofs);
    float nm = fmaxf(m, t);
    float c = __expf(m - nm), p = __expf(t - nm);
    s = s * c + p;
    o = o * c + p * v;
    m = nm;
  };

  for (; j + 1 < jend; j += 2) {
    int sa = bucket[j], sb = bucket[j + 1];
    float va = xl[(size_t)sa * 32 + lane];
    float vb = xl[(size_t)sb * 32 + lane];
    update(va);
    update(vb);
  }
  if (j < jend) update(xl[(size_t)bucket[j] * 32 + lane]);
  out[(size_t)node * 32 + lane] = o / s + b[lane];
}

extern "C" void kernel_launch(void* const* d_in, const int* in_sizes, int n_in,
                              void* d_out, int out_size, void* d_ws, size_t ws_size,
                              hipStream_t stream) {
  const float* x    = (const float*)d_in[0];
  const void*  ei   = d_in[1];
  const float* Wl1  = (const float*)d_in[2];
  const float* Wr1  = (const float*)d_in[3];
  const float* att1 = (const float*)d_in[4];
  const float* b1   = (const float*)d_in[5];
  const float* Wl2  = (const float*)d_in[6];
  const float* Wr2  = (const float*)d_in[7];
  const float* att2 = (const float*)d_in[8];
  const float* b2   = (const float*)d_in[9];

  const int N = in_sizes[0] / 128;
  const int E = in_sizes[1] / 2;
  const int Etot = E + N;
  float* out = (float*)d_out;
  (void)out_size; (void)n_in; (void)ws_size;

  // ---------------- workspace layout ----------------
  char* ws = (char*)d_ws;
  size_t off_b = 0;
  auto alloc = [&](size_t bytes) {
    void* p = ws + off_b;
    off_b += (bytes + 255) & ~(size_t)255;
    return p;
  };
  float* xl1    = (float*)alloc((size_t)N * 128 * 4);  // layer-2 xl2/xr2 overlay here later
  float* xr1    = (float*)alloc((size_t)N * 128 * 4);
  float* h1     = (float*)alloc((size_t)N * 128 * 4);
  int*   bucket = (int*)alloc((size_t)Etot * 4);
  int*   csroff = (int*)alloc((size_t)(N + 1) * 4);
  int*   cursor = (int*)alloc((size_t)N * 4);
  int*   count  = (int*)alloc((size_t)N * 4);
  int*   bsum   = (int*)alloc(256 * 4);
  int*   flag   = (int*)alloc(256);

  // layer-2 transforms overlay the (then-dead) xl1/xr1 region
  float* xl2 = xl1;
  float* xr2 = xl1 + (size_t)N * 32;

  const int nscan = (N + 255) / 256;  // <= 256 blocks

  // ---------------- CSR build (shared by both layers) ----------------
  hipLaunchKernelGGL(detect_idx64, dim3(1), dim3(64), 0, stream, ei, N, flag);
  hipMemsetAsync(count, 0, (size_t)N * 4, stream);
  hipLaunchKernelGGL(hist_k, dim3((Etot + 255) / 256), dim3(256), 0, stream, ei, flag, count, E, Etot);
  hipLaunchKernelGGL(scan1_k, dim3(nscan), dim3(256), 0, stream, count, bsum, N);
  hipLaunchKernelGGL(scan2_k, dim3(1), dim3(256), 0, stream, bsum, nscan);
  hipLaunchKernelGGL(scan3_k, dim3(nscan), dim3(256), 0, stream, count, bsum, csroff, cursor, N, Etot);
  hipLaunchKernelGGL(scatter_k, dim3((Etot + 255) / 256), dim3(256), 0, stream, ei, flag, cursor, bucket, E, Etot);

  // ---------------- layer 1 ----------------
  hipLaunchKernelGGL((dual_gemm<128, 128>), dim3((N + 1) / 2), dim3(256), 0, stream,
                     x, Wl1, Wr1, xl1, xr1, N);
  hipLaunchKernelGGL(fused_layer1_k, dim3((N + 3) / 4), dim3(256), 0, stream,
                     xl1, xr1, csroff, bucket, att1, b1, h1, N);

  // ---------------- layer 2 ----------------
  hipLaunchKernelGGL((dual_gemm<128, 32>), dim3((N + 7) / 8), dim3(256), 0, stream,
                     h1, Wl2, Wr2, xl2, xr2, N);
  hipLaunchKernelGGL(fused_layer2_k, dim3((N + 7) / 8), dim3(256), 0, stream,
                     xl2, xr2, csroff, bucket, att2, b2, out, N);
}

// Round 3
// 331.237 us; speedup vs baseline: 3.3233x; 1.4803x over previous
//
#include <hip/hip_runtime.h>

#define NEG 0.2f

// ---------- detect whether edge_index arrived as int64 or int32 ----------
__global__ void detect_idx64(const void* __restrict__ ei, int n_nodes, int* __restrict__ flag) {
  const long long* e64 = (const long long*)ei;
  long long v = e64[threadIdx.x];
  bool ok = (v >= 0 && v < (long long)n_nodes);
  unsigned long long b = __ballot(ok);
  if (threadIdx.x == 0) *flag = (b == ~0ull) ? 1 : 0;
}

__device__ __forceinline__ void get_edge(const void* __restrict__ ei, int is64, int e, int E,
                                         int& src, int& dst) {
  if (e >= E) { src = e - E; dst = e - E; return; }  // self-loops appended
  if (is64) {
    const long long* p = (const long long*)ei;
    src = (int)p[e];
    dst = (int)p[(size_t)E + e];
  } else {
    const int* p = (const int*)ei;
    src = p[e];
    dst = p[E + e];
  }
}

// ---------- CSR build: histogram -> scan -> scatter ----------
__global__ void hist_k(const void* __restrict__ ei, const int* __restrict__ flag,
                       int* __restrict__ count, int E, int Etot) {
  int e = blockIdx.x * 256 + threadIdx.x;
  if (e >= Etot) return;
  int src, dst;
  get_edge(ei, *flag, e, E, src, dst);
  (void)src;
  atomicAdd(&count[dst], 1);
}

__global__ void scan1_k(const int* __restrict__ count, int* __restrict__ bsum, int n) {
  __shared__ int sd[256];
  int i = blockIdx.x * 256 + threadIdx.x;
  sd[threadIdx.x] = (i < n) ? count[i] : 0;
  __syncthreads();
  for (int o = 128; o; o >>= 1) {
    if (threadIdx.x < o) sd[threadIdx.x] += sd[threadIdx.x + o];
    __syncthreads();
  }
  if (threadIdx.x == 0) bsum[blockIdx.x] = sd[0];
}

__global__ void scan2_k(int* __restrict__ bsum, int nb) {  // exclusive scan, 1 block, nb<=256
  __shared__ int sd[256];
  int v = (threadIdx.x < nb) ? bsum[threadIdx.x] : 0;
  sd[threadIdx.x] = v;
  __syncthreads();
  for (int o = 1; o < 256; o <<= 1) {
    int t = (threadIdx.x >= o) ? sd[threadIdx.x - o] : 0;
    __syncthreads();
    sd[threadIdx.x] += t;
    __syncthreads();
  }
  if (threadIdx.x < nb) bsum[threadIdx.x] = sd[threadIdx.x] - v;
}

__global__ void scan3_k(const int* __restrict__ count, const int* __restrict__ bsum,
                        int* __restrict__ off, int* __restrict__ cursor, int n, int etot) {
  __shared__ int sd[256];
  int i = blockIdx.x * 256 + threadIdx.x;
  int v = (i < n) ? count[i] : 0;
  sd[threadIdx.x] = v;
  __syncthreads();
  for (int o = 1; o < 256; o <<= 1) {
    int t = (threadIdx.x >= o) ? sd[threadIdx.x - o] : 0;
    __syncthreads();
    sd[threadIdx.x] += t;
    __syncthreads();
  }
  if (i < n) {
    int ex = bsum[blockIdx.x] + sd[threadIdx.x] - v;
    off[i] = ex;
    cursor[i] = ex;
  }
  if (i == 0) off[n] = etot;
}

__global__ void scatter_k(const void* __restrict__ ei, const int* __restrict__ flag,
                          int* __restrict__ cursor, int* __restrict__ bucket, int E, int Etot) {
  int e = blockIdx.x * 256 + threadIdx.x;
  if (e >= Etot) return;
  int src, dst;
  get_edge(ei, *flag, e, E, src, dst);
  int pos = atomicAdd(&cursor[dst], 1);
  bucket[pos] = src;
}

// ---------- tiled dual GEMM: [xl|xr] = X @ [Wl|Wr], K=128 fixed ----------
// Block: 256 threads, TM rows x 2C cols. Thread: RPT x CPT register tile.
// TCG col-groups: tc = tid % TCG (CPT cols each), tr = tid / TCG (RPT rows each).
template <int C, int TM, int TCG, int RPT, int CPT>
__global__ void dual_gemm_t(const float* __restrict__ X,
                            const float* __restrict__ Wl,
                            const float* __restrict__ Wr,
                            float* __restrict__ xl, float* __restrict__ xr, int nrows) {
  constexpr int K = 128, KT = 32;
  constexpr int W2 = 2 * C;
  __shared__ float xsT[KT][TM];   // transposed X tile
  __shared__ float ws[KT][W2];    // [Wl | Wr] tile
  const int tid = threadIdx.x;
  const int tc = tid % TCG, tr = tid / TCG;
  const int row0 = blockIdx.x * TM;
  float acc[RPT][CPT] = {};

  for (int k0 = 0; k0 < K; k0 += KT) {
    // X tile: TM*KT floats, float4 per thread, store transposed
    constexpr int XF4 = TM * KT / 4 / 256;
#pragma unroll
    for (int i = 0; i < XF4; ++i) {
      int f = tid + i * 256;
      int row = f / (KT / 4), j = f % (KT / 4);
      float4 v = make_float4(0.f, 0.f, 0.f, 0.f);
      if (row0 + row < nrows) v = *(const float4*)&X[(size_t)(row0 + row) * K + k0 + 4 * j];
      xsT[4 * j + 0][row] = v.x;
      xsT[4 * j + 1][row] = v.y;
      xsT[4 * j + 2][row] = v.z;
      xsT[4 * j + 3][row] = v.w;
    }
    // W tiles: KT*C floats each
    constexpr int WF4 = KT * C / 4 / 256;
#pragma unroll
    for (int i = 0; i < WF4; ++i) {
      int f = tid + i * 256;
      int kk = f / (C / 4), c4 = f % (C / 4);
      *(float4*)&ws[kk][c4 * 4]     = *(const float4*)&Wl[(size_t)(k0 + kk) * C + c4 * 4];
      *(float4*)&ws[kk][C + c4 * 4] = *(const float4*)&Wr[(size_t)(k0 + kk) * C + c4 * 4];
    }
    __syncthreads();
#pragma unroll 4
    for (int kk = 0; kk < KT; ++kk) {
      float xv[RPT], wv[CPT];
#pragma unroll
      for (int i = 0; i < RPT; i += 4) *(float4*)&xv[i] = *(const float4*)&xsT[kk][tr * RPT + i];
#pragma unroll
      for (int j = 0; j < CPT; j += 4) *(float4*)&wv[j] = *(const float4*)&ws[kk][tc * CPT + j];
#pragma unroll
      for (int i = 0; i < RPT; ++i)
#pragma unroll
        for (int j = 0; j < CPT; ++j) acc[i][j] = fmaf(xv[i], wv[j], acc[i][j]);
    }
    __syncthreads();
  }

  const int c0 = tc * CPT;  // entirely within xl (c0<C) or xr (c0>=C) since C%CPT==0
#pragma unroll
  for (int i = 0; i < RPT; ++i) {
    int row = row0 + tr * RPT + i;
    if (row >= nrows) break;
    if (c0 < C) {
#pragma unroll
      for (int j = 0; j < CPT; j += 4)
        *(float4*)&xl[(size_t)row * C + c0 + j] = *(float4*)&acc[i][j];
    } else {
#pragma unroll
      for (int j = 0; j < CPT; j += 4)
        *(float4*)&xr[(size_t)row * C + (c0 - C) + j] = *(float4*)&acc[i][j];
    }
  }
}

// ---------- layer 1 fused: one wave per node, online softmax ----------
__global__ void fused_layer1_k(const float* __restrict__ xl, const float* __restrict__ xr,
                               const int* __restrict__ off, const int* __restrict__ bucket,
                               const float* __restrict__ att, const float* __restrict__ b,
                               float* __restrict__ h1, int N) {
  int node = blockIdx.x * 4 + (threadIdx.x >> 6);
  int lane = threadIdx.x & 63;
  if (node >= N) return;
  float xr0 = xr[(size_t)node * 128 + lane];
  float xr1 = xr[(size_t)node * 128 + 64 + lane];
  float a0 = att[lane], a1 = att[64 + lane];
  float m0 = -INFINITY, m1 = -INFINITY, s0 = 0.f, s1 = 0.f, o0 = 0.f, o1 = 0.f;
  int jend = off[node + 1];
  int j = off[node];

  auto update = [&](float v0, float v1) {
    float e0 = v0 + xr0; e0 = e0 > 0.f ? e0 : NEG * e0;
    float e1 = v1 + xr1; e1 = e1 > 0.f ? e1 : NEG * e1;
    float t0 = e0 * a0, t1 = e1 * a1;
#pragma unroll
    for (int o = 32; o; o >>= 1) {
      t0 += __shfl_xor(t0, o);
      t1 += __shfl_xor(t1, o);
    }
    float nm0 = fmaxf(m0, t0), nm1 = fmaxf(m1, t1);
    float c0 = __expf(m0 - nm0), c1 = __expf(m1 - nm1);
    float p0 = __expf(t0 - nm0), p1 = __expf(t1 - nm1);
    s0 = s0 * c0 + p0;
    s1 = s1 * c1 + p1;
    o0 = o0 * c0 + p0 * v0;
    o1 = o1 * c1 + p1 * v1;
    m0 = nm0;
    m1 = nm1;
  };

  for (; j + 1 < jend; j += 2) {
    int sa = bucket[j], sb = bucket[j + 1];
    const float* pa = xl + (size_t)sa * 128;
    const float* pb = xl + (size_t)sb * 128;
    float va0 = pa[lane], va1 = pa[64 + lane];
    float vb0 = pb[lane], vb1 = pb[64 + lane];
    update(va0, va1);
    update(vb0, vb1);
  }
  if (j < jend) {
    const float* pa = xl + (size_t)bucket[j] * 128;
    update(pa[lane], pa[64 + lane]);
  }
  float v0 = o0 / s0 + b[lane];
  float v1 = o1 / s1 + b[64 + lane];
  h1[(size_t)node * 128 + lane]      = v0 > 0.f ? v0 : __expf(v0) - 1.f;  // ELU
  h1[(size_t)node * 128 + 64 + lane] = v1 > 0.f ? v1 : __expf(v1) - 1.f;
}

// ---------- layer 2 fused: half-wave per node ----------
__global__ void fused_layer2_k(const float* __restrict__ xl, const float* __restrict__ xr,
                               const int* __restrict__ off, const int* __restrict__ bucket,
                               const float* __restrict__ att, const float* __restrict__ b,
                               float* __restrict__ out, int N) {
  int node = blockIdx.x * 8 + (threadIdx.x >> 5);
  int lane = threadIdx.x & 31;
  if (node >= N) return;
  float xr0 = xr[(size_t)node * 32 + lane];
  float a0 = att[lane];
  float m = -INFINITY, s = 0.f, o = 0.f;
  int jend = off[node + 1];
  int j = off[node];

  auto update = [&](float v) {
    float e = v + xr0; e = e > 0.f ? e : NEG * e;
    float t = e * a0;
#pragma unroll
    for (int ofs = 16; ofs; ofs >>= 1) t += __shfl_xor(t, ofs);
    float nm = fmaxf(m, t);
    float c = __expf(m - nm), p = __expf(t - nm);
    s = s * c + p;
    o = o * c + p * v;
    m = nm;
  };

  for (; j + 1 < jend; j += 2) {
    int sa = bucket[j], sb = bucket[j + 1];
    float va = xl[(size_t)sa * 32 + lane];
    float vb = xl[(size_t)sb * 32 + lane];
    update(va);
    update(vb);
  }
  if (j < jend) update(xl[(size_t)bucket[j] * 32 + lane]);
  out[(size_t)node * 32 + lane] = o / s + b[lane];
}

extern "C" void kernel_launch(void* const* d_in, const int* in_sizes, int n_in,
                              void* d_out, int out_size, void* d_ws, size_t ws_size,
                              hipStream_t stream) {
  const float* x    = (const float*)d_in[0];
  const void*  ei   = d_in[1];
  const float* Wl1  = (const float*)d_in[2];
  const float* Wr1  = (const float*)d_in[3];
  const float* att1 = (const float*)d_in[4];
  const float* b1   = (const float*)d_in[5];
  const float* Wl2  = (const float*)d_in[6];
  const float* Wr2  = (const float*)d_in[7];
  const float* att2 = (const float*)d_in[8];
  const float* b2   = (const float*)d_in[9];

  const int N = in_sizes[0] / 128;
  const int E = in_sizes[1] / 2;
  const int Etot = E + N;
  float* out = (float*)d_out;
  (void)out_size; (void)n_in; (void)ws_size;

  // ---------------- workspace layout ----------------
  char* ws = (char*)d_ws;
  size_t off_b = 0;
  auto alloc = [&](size_t bytes) {
    void* p = ws + off_b;
    off_b += (bytes + 255) & ~(size_t)255;
    return p;
  };
  float* xl1    = (float*)alloc((size_t)N * 128 * 4);  // layer-2 xl2/xr2 overlay here later
  float* xr1    = (float*)alloc((size_t)N * 128 * 4);
  float* h1     = (float*)alloc((size_t)N * 128 * 4);
  int*   bucket = (int*)alloc((size_t)Etot * 4);
  int*   csroff = (int*)alloc((size_t)(N + 1) * 4);
  int*   cursor = (int*)alloc((size_t)N * 4);
  int*   count  = (int*)alloc((size_t)N * 4);
  int*   bsum   = (int*)alloc(256 * 4);
  int*   flag   = (int*)alloc(256);

  // layer-2 transforms overlay the (then-dead) xl1/xr1 region
  float* xl2 = xl1;
  float* xr2 = xl1 + (size_t)N * 32;

  const int nscan = (N + 255) / 256;  // <= 256 blocks

  // ---------------- CSR build (shared by both layers) ----------------
  hipLaunchKernelGGL(detect_idx64, dim3(1), dim3(64), 0, stream, ei, N, flag);
  hipMemsetAsync(count, 0, (size_t)N * 4, stream);
  hipLaunchKernelGGL(hist_k, dim3((Etot + 255) / 256), dim3(256), 0, stream, ei, flag, count, E, Etot);
  hipLaunchKernelGGL(scan1_k, dim3(nscan), dim3(256), 0, stream, count, bsum, N);
  hipLaunchKernelGGL(scan2_k, dim3(1), dim3(256), 0, stream, bsum, nscan);
  hipLaunchKernelGGL(scan3_k, dim3(nscan), dim3(256), 0, stream, count, bsum, csroff, cursor, N, Etot);
  hipLaunchKernelGGL(scatter_k, dim3((Etot + 255) / 256), dim3(256), 0, stream, ei, flag, cursor, bucket, E, Etot);

  // ---------------- layer 1 ----------------
  // C=128: TM=64, 32 col-groups, 8x8 per thread. LDS = 8KB + 32KB = 40KB.
  hipLaunchKernelGGL((dual_gemm_t<128, 64, 32, 8, 8>), dim3((N + 63) / 64), dim3(256), 0, stream,
                     x, Wl1, Wr1, xl1, xr1, N);
  hipLaunchKernelGGL(fused_layer1_k, dim3((N + 3) / 4), dim3(256), 0, stream,
                     xl1, xr1, csroff, bucket, att1, b1, h1, N);

  // ---------------- layer 2 ----------------
  // C=32: TM=128, 8 col-groups, 4x8 per thread. LDS = 16KB + 8KB = 24KB.
  hipLaunchKernelGGL((dual_gemm_t<32, 128, 8, 4, 8>), dim3((N + 127) / 128), dim3(256), 0, stream,
                     h1, Wl2, Wr2, xl2, xr2, N);
  hipLaunchKernelGGL(fused_layer2_k, dim3((N + 7) / 8), dim3(256), 0, stream,
                     xl2, xr2, csroff, bucket, att2, b2, out, N);
}

// Round 4
// 270.719 us; speedup vs baseline: 4.0663x; 1.2235x over previous
//
#include <hip/hip_runtime.h>

#define NEG 0.2f

// ---------- bf16 pack/unpack (RNE) ----------
__device__ __forceinline__ float blo(unsigned u) { return __uint_as_float(u << 16); }
__device__ __forceinline__ float bhi(unsigned u) { return __uint_as_float(u & 0xffff0000u); }
__device__ __forceinline__ unsigned bpack(float a, float b) {
  unsigned ua = __float_as_uint(a), ub = __float_as_uint(b);
  unsigned ra = (ua + 0x7fffu + ((ua >> 16) & 1u)) >> 16;
  unsigned rb = (ub + 0x7fffu + ((ub >> 16) & 1u)) >> 16;
  return ra | (rb << 16);
}

// ---------- detect whether edge_index arrived as int64 or int32 ----------
__global__ void detect_idx64(const void* __restrict__ ei, int n_nodes, int* __restrict__ flag) {
  const long long* e64 = (const long long*)ei;
  long long v = e64[threadIdx.x];
  bool ok = (v >= 0 && v < (long long)n_nodes);
  unsigned long long b = __ballot(ok);
  if (threadIdx.x == 0) *flag = (b == ~0ull) ? 1 : 0;
}

__device__ __forceinline__ void get_edge(const void* __restrict__ ei, int is64, int e, int E,
                                         int& src, int& dst) {
  if (e >= E) { src = e - E; dst = e - E; return; }  // self-loops appended
  if (is64) {
    const long long* p = (const long long*)ei;
    src = (int)p[e];
    dst = (int)p[(size_t)E + e];
  } else {
    const int* p = (const int*)ei;
    src = p[e];
    dst = p[E + e];
  }
}

// ---------- CSR build: histogram -> scan -> scatter ----------
__global__ void hist_k(const void* __restrict__ ei, const int* __restrict__ flag,
                       int* __restrict__ count, int E, int Etot) {
  int e = blockIdx.x * 256 + threadIdx.x;
  if (e >= Etot) return;
  int src, dst;
  get_edge(ei, *flag, e, E, src, dst);
  (void)src;
  atomicAdd(&count[dst], 1);
}

__global__ void scan1_k(const int* __restrict__ count, int* __restrict__ bsum, int n) {
  __shared__ int sd[256];
  int i = blockIdx.x * 256 + threadIdx.x;
  sd[threadIdx.x] = (i < n) ? count[i] : 0;
  __syncthreads();
  for (int o = 128; o; o >>= 1) {
    if (threadIdx.x < o) sd[threadIdx.x] += sd[threadIdx.x + o];
    __syncthreads();
  }
  if (threadIdx.x == 0) bsum[blockIdx.x] = sd[0];
}

__global__ void scan2_k(int* __restrict__ bsum, int nb) {  // exclusive scan, 1 block, nb<=256
  __shared__ int sd[256];
  int v = (threadIdx.x < nb) ? bsum[threadIdx.x] : 0;
  sd[threadIdx.x] = v;
  __syncthreads();
  for (int o = 1; o < 256; o <<= 1) {
    int t = (threadIdx.x >= o) ? sd[threadIdx.x - o] : 0;
    __syncthreads();
    sd[threadIdx.x] += t;
    __syncthreads();
  }
  if (threadIdx.x < nb) bsum[threadIdx.x] = sd[threadIdx.x] - v;
}

__global__ void scan3_k(const int* __restrict__ count, const int* __restrict__ bsum,
                        int* __restrict__ off, int* __restrict__ cursor, int n, int etot) {
  __shared__ int sd[256];
  int i = blockIdx.x * 256 + threadIdx.x;
  int v = (i < n) ? count[i] : 0;
  sd[threadIdx.x] = v;
  __syncthreads();
  for (int o = 1; o < 256; o <<= 1) {
    int t = (threadIdx.x >= o) ? sd[threadIdx.x - o] : 0;
    __syncthreads();
    sd[threadIdx.x] += t;
    __syncthreads();
  }
  if (i < n) {
    int ex = bsum[blockIdx.x] + sd[threadIdx.x] - v;
    off[i] = ex;
    cursor[i] = ex;
  }
  if (i == 0) off[n] = etot;
}

__global__ void scatter_k(const void* __restrict__ ei, const int* __restrict__ flag,
                          int* __restrict__ cursor, int* __restrict__ bucket, int E, int Etot) {
  int e = blockIdx.x * 256 + threadIdx.x;
  if (e >= Etot) return;
  int src, dst;
  get_edge(ei, *flag, e, E, src, dst);
  int pos = atomicAdd(&cursor[dst], 1);
  bucket[pos] = src;
}

// ---------- tiled dual GEMM with packed-pair bf16 epilogue ----------
// [xl|xr] = X @ [Wl|Wr], K=128. Output written as packed bf16 pairs:
// out_p[row][q] = pack(col_a(q), col_a(q)+HS/2) where
// col_a(q) = (q/(HS/2))*HS + q%(HS/2)   (HS = per-head width).
// Thread tc owns pair-groups 4tc..4tc+3 (CPT=8 cols as 4 pairs).
template <int C, int TM, int TCG, int RPT, int HS>
__global__ void dual_gemm_p(const float* __restrict__ X,
                            const float* __restrict__ Wl,
                            const float* __restrict__ Wr,
                            unsigned* __restrict__ xl_p, unsigned* __restrict__ xr_p, int nrows) {
  constexpr int K = 128, KT = 32, W2 = 2 * C, NPM = C / 2, PS = HS / 2;
  __shared__ float xsT[KT][TM];   // transposed X tile
  __shared__ float ws[KT][W2];    // [Wl | Wr] tile
  const int tid = threadIdx.x;
  const int tc = tid % TCG, tr = tid / TCG;
  const int row0 = blockIdx.x * TM;
  const int mat = (4 * tc) / NPM;          // 0 -> xl, 1 -> xr
  const int q0 = (4 * tc) % NPM;           // pair index within matrix
  const int col_a0 = mat * C + (q0 / PS) * HS + (q0 % PS);
  float acc[RPT][8] = {};

  for (int k0 = 0; k0 < K; k0 += KT) {
    constexpr int XF4 = TM * KT / 4 / 256;
#pragma unroll
    for (int i = 0; i < XF4; ++i) {
      int f = tid + i * 256;
      int row = f / (KT / 4), j = f % (KT / 4);
      float4 v = make_float4(0.f, 0.f, 0.f, 0.f);
      if (row0 + row < nrows) v = *(const float4*)&X[(size_t)(row0 + row) * K + k0 + 4 * j];
      xsT[4 * j + 0][row] = v.x;
      xsT[4 * j + 1][row] = v.y;
      xsT[4 * j + 2][row] = v.z;
      xsT[4 * j + 3][row] = v.w;
    }
    constexpr int WF4 = KT * C / 4 / 256;
#pragma unroll
    for (int i = 0; i < WF4; ++i) {
      int f = tid + i * 256;
      int kk = f / (C / 4), c4 = f % (C / 4);
      *(float4*)&ws[kk][c4 * 4]     = *(const float4*)&Wl[(size_t)(k0 + kk) * C + c4 * 4];
      *(float4*)&ws[kk][C + c4 * 4] = *(const float4*)&Wr[(size_t)(k0 + kk) * C + c4 * 4];
    }
    __syncthreads();
#pragma unroll 4
    for (int kk = 0; kk < KT; ++kk) {
      float xv[RPT], wv[8];
#pragma unroll
      for (int i = 0; i < RPT; i += 4) *(float4*)&xv[i] = *(const float4*)&xsT[kk][tr * RPT + i];
      *(float4*)&wv[0] = *(const float4*)&ws[kk][col_a0];
      *(float4*)&wv[4] = *(const float4*)&ws[kk][col_a0 + PS];
#pragma unroll
      for (int i = 0; i < RPT; ++i)
#pragma unroll
        for (int j = 0; j < 8; ++j) acc[i][j] = fmaf(xv[i], wv[j], acc[i][j]);
    }
    __syncthreads();
  }

  unsigned* outp = (mat == 0) ? xl_p : xr_p;
#pragma unroll
  for (int i = 0; i < RPT; ++i) {
    int row = row0 + tr * RPT + i;
    if (row >= nrows) break;
    uint4 u;
    u.x = bpack(acc[i][0], acc[i][4]);
    u.y = bpack(acc[i][1], acc[i][5]);
    u.z = bpack(acc[i][2], acc[i][6]);
    u.w = bpack(acc[i][3], acc[i][7]);
    *(uint4*)&outp[(size_t)row * NPM + q0] = u;
  }
}

// ---------- layer 1 fused: wave per node, head-split half-waves, online softmax ----------
// Lane l<32: head0 pair (l, l+32); lane l>=32: head1 pair (32+l, 64+l).
__global__ void fused_layer1_k(const unsigned* __restrict__ xl_p, const unsigned* __restrict__ xr_p,
                               const int* __restrict__ off, const int* __restrict__ bucket,
                               const float* __restrict__ att, const float* __restrict__ b,
                               float* __restrict__ h1, int N) {
  int node = blockIdx.x * 4 + (threadIdx.x >> 6);
  int lane = threadIdx.x & 63;
  if (node >= N) return;
  int ch_a = (lane < 32) ? lane : 32 + lane;
  int ch_b = ch_a + 32;
  unsigned xru = xr_p[(size_t)node * 64 + lane];
  float xr_a = blo(xru), xr_b = bhi(xru);
  float att_a = att[ch_a], att_b = att[ch_b];
  float m = -INFINITY, s = 0.f, oa = 0.f, ob = 0.f;
  int j = off[node], jend = off[node + 1];

  auto upd = [&](unsigned vu) {
    float va = blo(vu), vb = bhi(vu);
    float ea = va + xr_a; ea = ea > 0.f ? ea : NEG * ea;
    float eb = vb + xr_b; eb = eb > 0.f ? eb : NEG * eb;
    float t = fmaf(ea, att_a, eb * att_b);
#pragma unroll
    for (int o = 1; o < 32; o <<= 1) t += __shfl_xor(t, o);  // per-half-wave reduce
    float nm = fmaxf(m, t);
    float c = __expf(m - nm), p = __expf(t - nm);
    s = fmaf(s, c, p);
    oa = fmaf(oa, c, p * va);
    ob = fmaf(ob, c, p * vb);
    m = nm;
  };

  for (; j + 1 < jend; j += 2) {
    unsigned va = xl_p[(size_t)bucket[j] * 64 + lane];
    unsigned vb = xl_p[(size_t)bucket[j + 1] * 64 + lane];
    upd(va);
    upd(vb);
  }
  if (j < jend) upd(xl_p[(size_t)bucket[j] * 64 + lane]);

  float inv = 1.f / s;
  float ra = fmaf(oa, inv, b[ch_a]);
  float rb = fmaf(ob, inv, b[ch_b]);
  h1[(size_t)node * 128 + ch_a] = ra > 0.f ? ra : __expf(ra) - 1.f;  // ELU
  h1[(size_t)node * 128 + ch_b] = rb > 0.f ? rb : __expf(rb) - 1.f;
}

// ---------- layer 2 fused: quarter-wave (16 lanes) per node ----------
// Lane l in [0,16): pair (l, l+16).
__global__ void fused_layer2_k(const unsigned* __restrict__ xl_p, const unsigned* __restrict__ xr_p,
                               const int* __restrict__ off, const int* __restrict__ bucket,
                               const float* __restrict__ att, const float* __restrict__ b,
                               float* __restrict__ out, int N) {
  int node = blockIdx.x * 16 + (threadIdx.x >> 4);
  int lane = threadIdx.x & 15;
  if (node >= N) return;
  unsigned xru = xr_p[(size_t)node * 16 + lane];
  float xr_a = blo(xru), xr_b = bhi(xru);
  float att_a = att[lane], att_b = att[lane + 16];
  float m = -INFINITY, s = 0.f, oa = 0.f, ob = 0.f;
  int j = off[node], jend = off[node + 1];

  auto upd = [&](unsigned vu) {
    float va = blo(vu), vb = bhi(vu);
    float ea = va + xr_a; ea = ea > 0.f ? ea : NEG * ea;
    float eb = vb + xr_b; eb = eb > 0.f ? eb : NEG * eb;
    float t = fmaf(ea, att_a, eb * att_b);
#pragma unroll
    for (int o = 1; o < 16; o <<= 1) t += __shfl_xor(t, o);  // per-quarter-wave reduce
    float nm = fmaxf(m, t);
    float c = __expf(m - nm), p = __expf(t - nm);
    s = fmaf(s, c, p);
    oa = fmaf(oa, c, p * va);
    ob = fmaf(ob, c, p * vb);
    m = nm;
  };

  for (; j + 1 < jend; j += 2) {
    unsigned va = xl_p[(size_t)bucket[j] * 16 + lane];
    unsigned vb = xl_p[(size_t)bucket[j + 1] * 16 + lane];
    upd(va);
    upd(vb);
  }
  if (j < jend) upd(xl_p[(size_t)bucket[j] * 16 + lane]);

  float inv = 1.f / s;
  out[(size_t)node * 32 + lane]      = fmaf(oa, inv, b[lane]);
  out[(size_t)node * 32 + 16 + lane] = fmaf(ob, inv, b[lane + 16]);
}

extern "C" void kernel_launch(void* const* d_in, const int* in_sizes, int n_in,
                              void* d_out, int out_size, void* d_ws, size_t ws_size,
                              hipStream_t stream) {
  const float* x    = (const float*)d_in[0];
  const void*  ei   = d_in[1];
  const float* Wl1  = (const float*)d_in[2];
  const float* Wr1  = (const float*)d_in[3];
  const float* att1 = (const float*)d_in[4];
  const float* b1   = (const float*)d_in[5];
  const float* Wl2  = (const float*)d_in[6];
  const float* Wr2  = (const float*)d_in[7];
  const float* att2 = (const float*)d_in[8];
  const float* b2   = (const float*)d_in[9];

  const int N = in_sizes[0] / 128;
  const int E = in_sizes[1] / 2;
  const int Etot = E + N;
  float* out = (float*)d_out;
  (void)out_size; (void)n_in; (void)ws_size;

  // ---------------- workspace layout ----------------
  char* ws = (char*)d_ws;
  size_t off_b = 0;
  auto alloc = [&](size_t bytes) {
    void* p = ws + off_b;
    off_b += (bytes + 255) & ~(size_t)255;
    return p;
  };
  unsigned* xl1p   = (unsigned*)alloc((size_t)N * 64 * 4);  // packed bf16 pairs
  unsigned* xr1p   = (unsigned*)alloc((size_t)N * 64 * 4);
  float*    h1     = (float*)alloc((size_t)N * 128 * 4);
  int*      bucket = (int*)alloc((size_t)Etot * 4);
  int*      csroff = (int*)alloc((size_t)(N + 1) * 4);
  int*      cursor = (int*)alloc((size_t)N * 4);
  int*      count  = (int*)alloc((size_t)N * 4);
  int*      bsum   = (int*)alloc(256 * 4);
  int*      flag   = (int*)alloc(256);

  // layer-2 packed transforms overlay the (then-dead) xl1p region
  unsigned* xl2p = xl1p;
  unsigned* xr2p = xl1p + (size_t)N * 16;

  const int nscan = (N + 255) / 256;  // <= 256 blocks

  // ---------------- CSR build (shared by both layers) ----------------
  hipLaunchKernelGGL(detect_idx64, dim3(1), dim3(64), 0, stream, ei, N, flag);
  hipMemsetAsync(count, 0, (size_t)N * 4, stream);
  hipLaunchKernelGGL(hist_k, dim3((Etot + 255) / 256), dim3(256), 0, stream, ei, flag, count, E, Etot);
  hipLaunchKernelGGL(scan1_k, dim3(nscan), dim3(256), 0, stream, count, bsum, N);
  hipLaunchKernelGGL(scan2_k, dim3(1), dim3(256), 0, stream, bsum, nscan);
  hipLaunchKernelGGL(scan3_k, dim3(nscan), dim3(256), 0, stream, count, bsum, csroff, cursor, N, Etot);
  hipLaunchKernelGGL(scatter_k, dim3((Etot + 255) / 256), dim3(256), 0, stream, ei, flag, cursor, bucket, E, Etot);

  // ---------------- layer 1 ----------------
  // C=128, HS=64: TM=64, 32 col-groups, 8 rows/thread. LDS = 8KB + 32KB.
  hipLaunchKernelGGL((dual_gemm_p<128, 64, 32, 8, 64>), dim3((N + 63) / 64), dim3(256), 0, stream,
                     x, Wl1, Wr1, xl1p, xr1p, N);
  hipLaunchKernelGGL(fused_layer1_k, dim3((N + 3) / 4), dim3(256), 0, stream,
                     xl1p, xr1p, csroff, bucket, att1, b1, h1, N);

  // ---------------- layer 2 ----------------
  // C=32, HS=32: TM=128, 8 col-groups, 4 rows/thread. LDS = 16KB + 8KB.
  hipLaunchKernelGGL((dual_gemm_p<32, 128, 8, 4, 32>), dim3((N + 127) / 128), dim3(256), 0, stream,
                     h1, Wl2, Wr2, xl2p, xr2p, N);
  hipLaunchKernelGGL(fused_layer2_k, dim3((N + 15) / 16), dim3(256), 0, stream,
                     xl2p, xr2p, csroff, bucket, att2, b2, out, N);
}